// Round 2
// baseline (335.671 us; speedup 1.0000x reference)
//
#include <hip/hip_runtime.h>

#define Bdim 32
#define Tdim 256
#define Cdim 1024
#define Mrows (Bdim * Tdim) /* 8192 */

typedef unsigned short u16;
typedef unsigned int u32;
typedef __bf16 bf16x8 __attribute__((ext_vector_type(8)));
typedef float f32x4 __attribute__((ext_vector_type(4)));

__device__ __forceinline__ float bf2f(u16 u) {
    union { u32 i; float f; } v; v.i = ((u32)u) << 16; return v.f;
}
__device__ __forceinline__ u16 f2bf(float f) {
    union { float f; u32 i; } v; v.f = f;
    u32 u = v.i;
    return (u16)((u + 0x7fffu + ((u >> 16) & 1u)) >> 16);  // RNE
}

__device__ __forceinline__ void gload16(const u16* g, u16* l) {
    __builtin_amdgcn_global_load_lds(
        (__attribute__((address_space(1))) const void*)g,
        (__attribute__((address_space(3))) void*)l, 16, 0, 0);
}

// ---- prep: xk/xv/xr = xx + (x - xx) * mix; f32 in, bf16 out --------------------
__global__ __launch_bounds__(256) void prep_kernel(
    const float* __restrict__ x, const float* __restrict__ tmk,
    const float* __restrict__ tmv, const float* __restrict__ tmr,
    u16* __restrict__ xk, u16* __restrict__ xv, u16* __restrict__ xr)
{
    int tid = blockIdx.x * 256 + threadIdx.x;   // 1,048,576 threads
    int e = tid << 3;                           // 8 elements per thread
    int c = e & (Cdim - 1);
    int t = (e >> 10) & (Tdim - 1);
    float xf[8], xxf[8], mk[8], mv[8], mr[8];
    *(float4*)(xf)     = *(const float4*)(x + e);
    *(float4*)(xf + 4) = *(const float4*)(x + e + 4);
    if (t != 0) {
        *(float4*)(xxf)     = *(const float4*)(x + e - Cdim);
        *(float4*)(xxf + 4) = *(const float4*)(x + e - Cdim + 4);
    } else {
#pragma unroll
        for (int j = 0; j < 8; j++) xxf[j] = 0.f;
    }
    *(float4*)(mk)     = *(const float4*)(tmk + c);
    *(float4*)(mk + 4) = *(const float4*)(tmk + c + 4);
    *(float4*)(mv)     = *(const float4*)(tmv + c);
    *(float4*)(mv + 4) = *(const float4*)(tmv + c + 4);
    *(float4*)(mr)     = *(const float4*)(tmr + c);
    *(float4*)(mr + 4) = *(const float4*)(tmr + c + 4);
    u16 ok[8], ov[8], orr[8];
#pragma unroll
    for (int j = 0; j < 8; j++) {
        float d = xf[j] - xxf[j];
        ok[j]  = f2bf(xxf[j] + d * mk[j]);
        ov[j]  = f2bf(xxf[j] + d * mv[j]);
        orr[j] = f2bf(xxf[j] + d * mr[j]);
    }
    *(uint4*)(xk + e) = *(const uint4*)ok;
    *(uint4*)(xv + e) = *(const uint4*)ov;
    *(uint4*)(xr + e) = *(const uint4*)orr;
}

// ---- weight convert: f32 -> bf16, 4 matrices ----------------------------------
__global__ __launch_bounds__(256) void wconv_kernel(
    const float* __restrict__ w0, const float* __restrict__ w1,
    const float* __restrict__ w2, const float* __restrict__ w3,
    u16* __restrict__ o0, u16* __restrict__ o1,
    u16* __restrict__ o2, u16* __restrict__ o3)
{
    const float* src; u16* dst;
    switch (blockIdx.y) {
        case 0: src = w0; dst = o0; break;
        case 1: src = w1; dst = o1; break;
        case 2: src = w2; dst = o2; break;
        default: src = w3; dst = o3; break;
    }
    int i = (blockIdx.x * 256 + threadIdx.x) << 3;  // 8 f32/thread; grid.x=512
    float a[8];
    *(float4*)(a)     = *(const float4*)(src + i);
    *(float4*)(a + 4) = *(const float4*)(src + i + 4);
    u16 o[8];
#pragma unroll
    for (int j = 0; j < 8; j++) o[j] = f2bf(a[j]);
    *(uint4*)(dst + i) = *(const uint4*)o;
}

// ---- GEMM: C[M,N] = A[M,K] * Bw[N,K]^T (bf16 in, f32 acc) ---------------------
// 128x128 tile, BK=32, 256 threads (4 waves, 2x2), 4x4 16x16x32 MFMAs per wave.
template <int BF16OUT>
__global__ __launch_bounds__(256) void gemm_bt(
    const u16* __restrict__ A, const u16* __restrict__ Bw,
    void* __restrict__ Cout, int M, int N, int K)
{
    __shared__ u16 As[128 * 32];
    __shared__ u16 Bs[128 * 32];
    const int tid = threadIdx.x;
    const int bm = blockIdx.y, bn = blockIdx.x;
    const int lane = tid & 63, wave = tid >> 6;
    const int wm = (wave & 1) << 6, wn = (wave >> 1) << 6;
    const int fr = lane & 15, quad = lane >> 4;

    const int srow = tid >> 2;
    const int skc = (tid & 3) << 3;
    const u16* ga = A + (size_t)(bm * 128 + srow) * K + skc;
    const u16* gb = Bw + (size_t)(bn * 128 + srow) * K + skc;
    u16* la = As + (wave << 9);   // wave-uniform LDS base; HW adds lane*16B
    u16* lb = Bs + (wave << 9);
    const size_t gstep = (size_t)64 * K;

    f32x4 acc[4][4];
#pragma unroll
    for (int i = 0; i < 4; i++)
#pragma unroll
        for (int j = 0; j < 4; j++)
            acc[i][j] = (f32x4){0.f, 0.f, 0.f, 0.f};

    for (int k0 = 0; k0 < K; k0 += 32) {
        __syncthreads();
        gload16(ga, la);
        gload16(ga + gstep, la + 2048);
        gload16(gb, lb);
        gload16(gb + gstep, lb + 2048);
        ga += 32; gb += 32;
        __syncthreads();
        bf16x8 af[4], bfr[4];
#pragma unroll
        for (int i = 0; i < 4; i++) {
            af[i]  = *(const bf16x8*)(As + (wm + i * 16 + fr) * 32 + quad * 8);
            bfr[i] = *(const bf16x8*)(Bs + (wn + i * 16 + fr) * 32 + quad * 8);
        }
#pragma unroll
        for (int i = 0; i < 4; i++)
#pragma unroll
            for (int j = 0; j < 4; j++)
                acc[i][j] = __builtin_amdgcn_mfma_f32_16x16x32_bf16(
                    af[i], bfr[j], acc[i][j], 0, 0, 0);
    }

    // C/D layout: row = quad*4 + reg, col = lane&15  [m89-verified]
    const int gr0 = bm * 128 + wm + quad * 4;
    const int gc0 = bn * 128 + wn + fr;
#pragma unroll
    for (int i = 0; i < 4; i++)
#pragma unroll
        for (int j = 0; j < 4; j++)
#pragma unroll
            for (int r = 0; r < 4; r++) {
                int gr = gr0 + i * 16 + r;
                int gc = gc0 + j * 16;
                float val = acc[i][j][r];
                if (BF16OUT)
                    ((u16*)Cout)[(size_t)gr * N + gc] = f2bf(val);
                else
                    ((float*)Cout)[(size_t)gr * N + gc] = val;
            }
}

// ---- WKV scan + sigmoid(r) gate; bf16 in, bf16 out ----------------------------
__global__ __launch_bounds__(64) void wkv_kernel(
    const u16* __restrict__ kb, const u16* __restrict__ vb,
    const u16* __restrict__ rb, const float* __restrict__ td,
    const float* __restrict__ tfirst, u16* __restrict__ rwkv)
{
    int gid = blockIdx.x * 64 + threadIdx.x;  // 0..32767 = (b, c)
    int b = gid >> 10, c = gid & (Cdim - 1);
    float w = -__expf(td[c]);
    float u = tfirst[c];
    size_t idx = (size_t)b * Tdim * Cdim + c;
    float p = 0.f, q = 0.f, o = -1e38f;
    for (int t = 0; t < Tdim; t++, idx += Cdim) {
        float kt = bf2f(kb[idx]), vt = bf2f(vb[idx]), rt = bf2f(rb[idx]);
        float no = fmaxf(o, u + kt);
        float A = __expf(o - no);
        float Bc = __expf(u + kt - no);
        float y = (A * p + Bc * vt) / (A * q + Bc);
        float sr = 1.0f / (1.0f + __expf(-rt));
        rwkv[idx] = f2bf(y * sr);
        float no2 = fmaxf(w + o, kt);
        float A2 = __expf(w + o - no2);
        float B2 = __expf(kt - no2);
        p = A2 * p + B2 * vt;
        q = A2 * q + B2;
        o = no2;
    }
}

extern "C" void kernel_launch(void* const* d_in, const int* in_sizes, int n_in,
                              void* d_out, int out_size, void* d_ws, size_t ws_size,
                              hipStream_t stream) {
    (void)in_sizes; (void)n_in; (void)out_size; (void)ws_size;
    const float* x   = (const float*)d_in[0];
    const float* td  = (const float*)d_in[1];
    const float* tfi = (const float*)d_in[2];
    const float* tmk = (const float*)d_in[3];
    const float* tmv = (const float*)d_in[4];
    const float* tmr = (const float*)d_in[5];
    const float* Wk  = (const float*)d_in[6];
    const float* Wv  = (const float*)d_in[7];
    const float* Wr  = (const float*)d_in[8];
    const float* Wo  = (const float*)d_in[9];

    char* ws = (char*)d_ws;
    const size_t MiB = (size_t)1 << 20;
    u16* xk    = (u16*)(ws);             // [0,16) MiB
    u16* xv    = (u16*)(ws + 16 * MiB);  // [16,32)
    u16* xr    = (u16*)(ws + 32 * MiB);  // [32,48)
    u16* wkb   = (u16*)(ws + 48 * MiB);  // [48,50)
    u16* wvb   = (u16*)(ws + 50 * MiB);  // [50,52)
    u16* wrb   = (u16*)(ws + 52 * MiB);  // [52,54)
    u16* wob   = (u16*)(ws + 54 * MiB);  // [54,56)
    u16* kb    = (u16*)(ws + 56 * MiB);  // [56,72)
    u16* vb    = (u16*)(ws + 72 * MiB);  // [72,88)
    u16* rb    = (u16*)(ws);             // [0,16) — overlaps xk (dead after gemm-k)
    u16* rwkvb = (u16*)(ws + 16 * MiB);  // [16,32) — overlaps xv (dead after gemm-v)

    prep_kernel<<<4096, 256, 0, stream>>>(x, tmk, tmv, tmr, xk, xv, xr);
    wconv_kernel<<<dim3(512, 4), 256, 0, stream>>>(Wk, Wv, Wr, Wo, wkb, wvb, wrb, wob);

    dim3 grid(Cdim / 128, Mrows / 128);  // (8, 64)
    gemm_bt<1><<<grid, 256, 0, stream>>>(xk, wkb, (void*)kb, Mrows, Cdim, Cdim);
    gemm_bt<1><<<grid, 256, 0, stream>>>(xv, wvb, (void*)vb, Mrows, Cdim, Cdim);
    gemm_bt<1><<<grid, 256, 0, stream>>>(xr, wrb, (void*)rb, Mrows, Cdim, Cdim);

    wkv_kernel<<<512, 64, 0, stream>>>(kb, vb, rb, td, tfi, rwkvb);

    gemm_bt<0><<<grid, 256, 0, stream>>>(rwkvb, wob, d_out, Mrows, Cdim, Cdim);
}

// Round 3
// 248.978 us; speedup vs baseline: 1.3482x; 1.3482x over previous
//
#include <hip/hip_runtime.h>

#define Bdim 32
#define Tdim 256
#define Cdim 1024
#define Mrows (Bdim * Tdim) /* 8192 */

typedef unsigned short u16;
typedef unsigned int u32;
typedef __bf16 bf16x8 __attribute__((ext_vector_type(8)));
typedef float f32x4 __attribute__((ext_vector_type(4)));

__device__ __forceinline__ float bf2f(u32 u) {
    union { u32 i; float f; } v; v.i = u << 16; return v.f;
}
__device__ __forceinline__ u16 f2bf(float f) {
    union { float f; u32 i; } v; v.f = f;
    u32 u = v.i;
    return (u16)((u + 0x7fffu + ((u >> 16) & 1u)) >> 16);  // RNE
}

__device__ __forceinline__ void gload16(const u16* g, u16* l) {
    __builtin_amdgcn_global_load_lds(
        (__attribute__((address_space(1))) const void*)g,
        (__attribute__((address_space(3))) void*)l, 16, 0, 0);
}

// ---- fused prep (x mixing -> bf16) + weight convert ---------------------------
__global__ __launch_bounds__(256) void prep_fused(
    const float* __restrict__ x, const float* __restrict__ tmk,
    const float* __restrict__ tmv, const float* __restrict__ tmr,
    u16* __restrict__ xk, u16* __restrict__ xv, u16* __restrict__ xr,
    const float* __restrict__ w0, const float* __restrict__ w1,
    const float* __restrict__ w2, const float* __restrict__ w3,
    u16* __restrict__ o0, u16* __restrict__ o1,
    u16* __restrict__ o2, u16* __restrict__ o3)
{
    int bid = blockIdx.x;
    if (bid < 4096) {
        int tid = bid * 256 + threadIdx.x;
        int e = tid << 3;
        int c = e & (Cdim - 1);
        int t = (e >> 10) & (Tdim - 1);
        float xf[8], xxf[8], mk[8], mv[8], mr[8];
        *(float4*)(xf)     = *(const float4*)(x + e);
        *(float4*)(xf + 4) = *(const float4*)(x + e + 4);
        if (t != 0) {
            *(float4*)(xxf)     = *(const float4*)(x + e - Cdim);
            *(float4*)(xxf + 4) = *(const float4*)(x + e - Cdim + 4);
        } else {
#pragma unroll
            for (int j = 0; j < 8; j++) xxf[j] = 0.f;
        }
        *(float4*)(mk)     = *(const float4*)(tmk + c);
        *(float4*)(mk + 4) = *(const float4*)(tmk + c + 4);
        *(float4*)(mv)     = *(const float4*)(tmv + c);
        *(float4*)(mv + 4) = *(const float4*)(tmv + c + 4);
        *(float4*)(mr)     = *(const float4*)(tmr + c);
        *(float4*)(mr + 4) = *(const float4*)(tmr + c + 4);
        u16 ok[8], ov[8], orr[8];
#pragma unroll
        for (int j = 0; j < 8; j++) {
            float d = xf[j] - xxf[j];
            ok[j]  = f2bf(xxf[j] + d * mk[j]);
            ov[j]  = f2bf(xxf[j] + d * mv[j]);
            orr[j] = f2bf(xxf[j] + d * mr[j]);
        }
        *(uint4*)(xk + e) = *(const uint4*)ok;
        *(uint4*)(xv + e) = *(const uint4*)ov;
        *(uint4*)(xr + e) = *(const uint4*)orr;
    } else {
        int wb = bid - 4096;                 // 0..2047
        int m = wb >> 9;                     // matrix 0..3
        const float* src; u16* dst;
        switch (m) {
            case 0: src = w0; dst = o0; break;
            case 1: src = w1; dst = o1; break;
            case 2: src = w2; dst = o2; break;
            default: src = w3; dst = o3; break;
        }
        int i = (((wb & 511) << 8) + threadIdx.x) << 3;
        float a[8];
        *(float4*)(a)     = *(const float4*)(src + i);
        *(float4*)(a + 4) = *(const float4*)(src + i + 4);
        u16 o[8];
#pragma unroll
        for (int j = 0; j < 8; j++) o[j] = f2bf(a[j]);
        *(uint4*)(dst + i) = *(const uint4*)o;
    }
}

// ---- GEMM body: C[8192,1024] = A[8192,1024] * Bw[1024,1024]^T (bf16 MFMA) -----
template <int BF16OUT>
__device__ __forceinline__ void gemm_body(
    const u16* __restrict__ A, const u16* __restrict__ Bw, void* __restrict__ Cout,
    u16* As, u16* Bs)
{
    const int K = Cdim, N = Cdim;
    const int tid = threadIdx.x;
    const int bm = blockIdx.y, bn = blockIdx.x;
    const int lane = tid & 63, wave = tid >> 6;
    const int wm = (wave & 1) << 6, wn = (wave >> 1) << 6;
    const int fr = lane & 15, quad = lane >> 4;

    const int srow = tid >> 2;
    const int skc = (tid & 3) << 3;
    const u16* ga = A + (size_t)(bm * 128 + srow) * K + skc;
    const u16* gb = Bw + (size_t)(bn * 128 + srow) * K + skc;
    u16* la = As + (wave << 9);   // wave-uniform LDS base; HW adds lane*16B
    u16* lb = Bs + (wave << 9);
    const size_t gstep = (size_t)64 * K;

    f32x4 acc[4][4];
#pragma unroll
    for (int i = 0; i < 4; i++)
#pragma unroll
        for (int j = 0; j < 4; j++)
            acc[i][j] = (f32x4){0.f, 0.f, 0.f, 0.f};

    for (int k0 = 0; k0 < K; k0 += 32) {
        __syncthreads();
        gload16(ga, la);
        gload16(ga + gstep, la + 2048);
        gload16(gb, lb);
        gload16(gb + gstep, lb + 2048);
        ga += 32; gb += 32;
        __syncthreads();
        bf16x8 af[4], bfr[4];
#pragma unroll
        for (int i = 0; i < 4; i++) {
            af[i]  = *(const bf16x8*)(As + (wm + i * 16 + fr) * 32 + quad * 8);
            bfr[i] = *(const bf16x8*)(Bs + (wn + i * 16 + fr) * 32 + quad * 8);
        }
#pragma unroll
        for (int i = 0; i < 4; i++)
#pragma unroll
            for (int j = 0; j < 4; j++)
                acc[i][j] = __builtin_amdgcn_mfma_f32_16x16x32_bf16(
                    af[i], bfr[j], acc[i][j], 0, 0, 0);
    }

    // C/D layout: row = quad*4 + reg, col = lane&15  [m89-verified]
    const int gr0 = bm * 128 + wm + quad * 4;
    const int gc0 = bn * 128 + wn + fr;
#pragma unroll
    for (int i = 0; i < 4; i++)
#pragma unroll
        for (int j = 0; j < 4; j++)
#pragma unroll
            for (int r = 0; r < 4; r++) {
                int gr = gr0 + i * 16 + r;
                int gc = gc0 + j * 16;
                float val = acc[i][j][r];
                if (BF16OUT)
                    ((u16*)Cout)[(size_t)gr * N + gc] = f2bf(val);
                else
                    ((float*)Cout)[(size_t)gr * N + gc] = val;
            }
}

// grouped GEMM for k/v/r (blockIdx.z selects operand set), bf16 out
__global__ __launch_bounds__(256) void gemm3_kernel(
    const u16* __restrict__ xk, const u16* __restrict__ xv, const u16* __restrict__ xr,
    const u16* __restrict__ wk, const u16* __restrict__ wv, const u16* __restrict__ wr,
    u16* __restrict__ ck, u16* __restrict__ cv, u16* __restrict__ cr)
{
    __shared__ u16 As[128 * 32];
    __shared__ u16 Bs[128 * 32];
    const u16* A; const u16* Bw; u16* Cout;
    switch (blockIdx.z) {
        case 0:  A = xk; Bw = wk; Cout = ck; break;
        case 1:  A = xv; Bw = wv; Cout = cv; break;
        default: A = xr; Bw = wr; Cout = cr; break;
    }
    gemm_body<1>(A, Bw, (void*)Cout, As, Bs);
}

// final GEMM, f32 out
__global__ __launch_bounds__(256) void gemmo_kernel(
    const u16* __restrict__ A, const u16* __restrict__ Bw, float* __restrict__ Cout)
{
    __shared__ u16 As[128 * 32];
    __shared__ u16 Bs[128 * 32];
    gemm_body<0>(A, Bw, (void*)Cout, As, Bs);
}

// ---- WKV scan + sigmoid(r) gate; register double-buffered prefetch ------------
#define WTC 16

#define LOADCHUNK(KA, VA, RA, T0)                                        \
    _Pragma("unroll")                                                    \
    for (int s = 0; s < WTC; s++) {                                      \
        size_t idx = base + (size_t)((T0) + s) * Cdim;                   \
        KA[s] = kb[idx]; VA[s] = vb[idx]; RA[s] = rb[idx];               \
    }

#define COMPCHUNK(KA, VA, RA, T0)                                        \
    _Pragma("unroll")                                                    \
    for (int s = 0; s < WTC; s++) {                                      \
        float kt = bf2f(KA[s]);                                          \
        float vt = bf2f(VA[s]);                                          \
        float rt = bf2f(RA[s]);                                          \
        float uk = u + kt;                                               \
        float no = fmaxf(o, uk);                                         \
        float Ae = __expf(o - no);                                       \
        float Bc = __expf(uk - no);                                      \
        float num = Ae * p + Bc * vt;                                    \
        float den = Ae * q + Bc;                                         \
        float y = num * __builtin_amdgcn_rcpf(den);                      \
        float sr = __builtin_amdgcn_rcpf(1.f + __expf(-rt));             \
        rwkv[base + (size_t)((T0) + s) * Cdim] = f2bf(y * sr);           \
        float wo = w + o;                                                \
        float no2 = fmaxf(wo, kt);                                       \
        float A2 = __expf(wo - no2);                                     \
        float B2 = __expf(kt - no2);                                     \
        p = A2 * p + B2 * vt;                                            \
        q = A2 * q + B2;                                                 \
        o = no2;                                                         \
    }

__global__ __launch_bounds__(64) void wkv_kernel(
    const u16* __restrict__ kb, const u16* __restrict__ vb,
    const u16* __restrict__ rb, const float* __restrict__ td,
    const float* __restrict__ tfirst, u16* __restrict__ rwkv)
{
    int lane = threadIdx.x;
    int blk = blockIdx.x;            // 512 blocks
    int b = blk >> 4;
    int c = ((blk & 15) << 6) + lane;
    float w = -__expf(td[c]);
    float u = tfirst[c];
    const size_t base = (size_t)b * Tdim * Cdim + c;

    u32 kA[WTC], vA[WTC], rA[WTC];
    u32 kB[WTC], vB[WTC], rB[WTC];
    float p = 0.f, q = 0.f, o = -1e38f;

    LOADCHUNK(kA, vA, rA, 0)
    for (int t0 = 0; t0 < Tdim; t0 += 2 * WTC) {
        LOADCHUNK(kB, vB, rB, t0 + WTC)
        COMPCHUNK(kA, vA, rA, t0)
        if (t0 + 2 * WTC < Tdim) {
            LOADCHUNK(kA, vA, rA, t0 + 2 * WTC)
        }
        COMPCHUNK(kB, vB, rB, t0 + WTC)
    }
}

extern "C" void kernel_launch(void* const* d_in, const int* in_sizes, int n_in,
                              void* d_out, int out_size, void* d_ws, size_t ws_size,
                              hipStream_t stream) {
    (void)in_sizes; (void)n_in; (void)out_size; (void)ws_size;
    const float* x   = (const float*)d_in[0];
    const float* td  = (const float*)d_in[1];
    const float* tfi = (const float*)d_in[2];
    const float* tmk = (const float*)d_in[3];
    const float* tmv = (const float*)d_in[4];
    const float* tmr = (const float*)d_in[5];
    const float* Wk  = (const float*)d_in[6];
    const float* Wv  = (const float*)d_in[7];
    const float* Wr  = (const float*)d_in[8];
    const float* Wo  = (const float*)d_in[9];

    char* ws = (char*)d_ws;
    const size_t MiB = (size_t)1 << 20;
    u16* xk    = (u16*)(ws);             // [0,16)
    u16* xv    = (u16*)(ws + 16 * MiB);  // [16,32)
    u16* xr    = (u16*)(ws + 32 * MiB);  // [32,48)
    u16* wkb   = (u16*)(ws + 48 * MiB);  // [48,50)
    u16* wvb   = (u16*)(ws + 50 * MiB);  // [50,52)
    u16* wrb   = (u16*)(ws + 52 * MiB);  // [52,54)
    u16* wob   = (u16*)(ws + 54 * MiB);  // [54,56)
    u16* kb    = (u16*)(ws + 56 * MiB);  // [56,72)
    u16* vb    = (u16*)(ws + 72 * MiB);  // [72,88)
    u16* rb    = (u16*)(ws + 88 * MiB);  // [88,104) — no alias: gemm3 z's run concurrently
    u16* rwkvb = (u16*)(ws);             // [0,16) — overlaps xk (dead after gemm3)

    prep_fused<<<6144, 256, 0, stream>>>(x, tmk, tmv, tmr, xk, xv, xr,
                                         Wk, Wv, Wr, Wo, wkb, wvb, wrb, wob);

    gemm3_kernel<<<dim3(8, 64, 3), 256, 0, stream>>>(xk, xv, xr, wkb, wvb, wrb,
                                                     kb, vb, rb);

    wkv_kernel<<<512, 64, 0, stream>>>(kb, vb, rb, td, tfi, rwkvb);

    gemmo_kernel<<<dim3(8, 64), 256, 0, stream>>>(rwkvb, wob, (float*)d_out);
}

// Round 4
// 229.017 us; speedup vs baseline: 1.4657x; 1.0872x over previous
//
#include <hip/hip_runtime.h>

#define Bdim 32
#define Tdim 256
#define Cdim 1024
#define Mrows (Bdim * Tdim) /* 8192 */

typedef unsigned short u16;
typedef unsigned int u32;
typedef __bf16 bf16x8 __attribute__((ext_vector_type(8)));
typedef float f32x4 __attribute__((ext_vector_type(4)));

__device__ __forceinline__ float bf2f(u32 u) {
    union { u32 i; float f; } v; v.i = u << 16; return v.f;
}
__device__ __forceinline__ u16 f2bf(float f) {
    union { float f; u32 i; } v; v.f = f;
    u32 u = v.i;
    return (u16)((u + 0x7fffu + ((u >> 16) & 1u)) >> 16);  // RNE
}

__device__ __forceinline__ void gload16(const u16* g, u16* l) {
    __builtin_amdgcn_global_load_lds(
        (__attribute__((address_space(1))) const void*)g,
        (__attribute__((address_space(3))) void*)l, 16, 0, 0);
}

// ---- fused prep (x mixing -> bf16) + weight convert ---------------------------
__global__ __launch_bounds__(256) void prep_fused(
    const float* __restrict__ x, const float* __restrict__ tmk,
    const float* __restrict__ tmv, const float* __restrict__ tmr,
    u16* __restrict__ xk, u16* __restrict__ xv, u16* __restrict__ xr,
    const float* __restrict__ w0, const float* __restrict__ w1,
    const float* __restrict__ w2, const float* __restrict__ w3,
    u16* __restrict__ o0, u16* __restrict__ o1,
    u16* __restrict__ o2, u16* __restrict__ o3)
{
    int bid = blockIdx.x;
    if (bid < 4096) {
        int tid = bid * 256 + threadIdx.x;
        int e = tid << 3;
        int c = e & (Cdim - 1);
        int t = (e >> 10) & (Tdim - 1);
        float xf[8], xxf[8], mk[8], mv[8], mr[8];
        *(float4*)(xf)     = *(const float4*)(x + e);
        *(float4*)(xf + 4) = *(const float4*)(x + e + 4);
        if (t != 0) {
            *(float4*)(xxf)     = *(const float4*)(x + e - Cdim);
            *(float4*)(xxf + 4) = *(const float4*)(x + e - Cdim + 4);
        } else {
#pragma unroll
            for (int j = 0; j < 8; j++) xxf[j] = 0.f;
        }
        *(float4*)(mk)     = *(const float4*)(tmk + c);
        *(float4*)(mk + 4) = *(const float4*)(tmk + c + 4);
        *(float4*)(mv)     = *(const float4*)(tmv + c);
        *(float4*)(mv + 4) = *(const float4*)(tmv + c + 4);
        *(float4*)(mr)     = *(const float4*)(tmr + c);
        *(float4*)(mr + 4) = *(const float4*)(tmr + c + 4);
        u16 ok[8], ov[8], orr[8];
#pragma unroll
        for (int j = 0; j < 8; j++) {
            float d = xf[j] - xxf[j];
            ok[j]  = f2bf(xxf[j] + d * mk[j]);
            ov[j]  = f2bf(xxf[j] + d * mv[j]);
            orr[j] = f2bf(xxf[j] + d * mr[j]);
        }
        *(uint4*)(xk + e) = *(const uint4*)ok;
        *(uint4*)(xv + e) = *(const uint4*)ov;
        *(uint4*)(xr + e) = *(const uint4*)orr;
    } else {
        int wb = bid - 4096;                 // 0..2047
        int m = wb >> 9;                     // matrix 0..3
        const float* src; u16* dst;
        switch (m) {
            case 0: src = w0; dst = o0; break;
            case 1: src = w1; dst = o1; break;
            case 2: src = w2; dst = o2; break;
            default: src = w3; dst = o3; break;
        }
        int i = (((wb & 511) << 8) + threadIdx.x) << 3;
        float a[8];
        *(float4*)(a)     = *(const float4*)(src + i);
        *(float4*)(a + 4) = *(const float4*)(src + i + 4);
        u16 o[8];
#pragma unroll
        for (int j = 0; j < 8; j++) o[j] = f2bf(a[j]);
        *(uint4*)(dst + i) = *(const uint4*)o;
    }
}

// ---- GEMM body: C[8192,1024] = A[8192,1024] * Bw[1024,1024]^T (bf16 MFMA) -----
// 128x128 tile, BK=64 (two 32-wide LDS buffer pairs per barrier-pair),
// 256 threads (4 waves, 2x2), 32 MFMAs per barrier-pair.
template <int BF16OUT>
__device__ __forceinline__ void gemm_body(
    const u16* __restrict__ A, const u16* __restrict__ Bw, void* __restrict__ Cout,
    u16* As0, u16* Bs0, u16* As1, u16* Bs1, int bm, int bn)
{
    const int K = Cdim, N = Cdim;
    const int tid = threadIdx.x;
    const int lane = tid & 63, wave = tid >> 6;
    const int wm = (wave & 1) << 6, wn = (wave >> 1) << 6;
    const int fr = lane & 15, quad = lane >> 4;

    const int srow = tid >> 2;
    const int skc = (tid & 3) << 3;
    const u16* ga = A + (size_t)(bm * 128 + srow) * K + skc;
    const u16* gb = Bw + (size_t)(bn * 128 + srow) * K + skc;
    u16* la0 = As0 + (wave << 9);   // wave-uniform LDS base; HW adds lane*16B
    u16* lb0 = Bs0 + (wave << 9);
    u16* la1 = As1 + (wave << 9);
    u16* lb1 = Bs1 + (wave << 9);
    const size_t gstep = (size_t)64 * K;

    f32x4 acc[4][4];
#pragma unroll
    for (int i = 0; i < 4; i++)
#pragma unroll
        for (int j = 0; j < 4; j++)
            acc[i][j] = (f32x4){0.f, 0.f, 0.f, 0.f};

    for (int k0 = 0; k0 < K; k0 += 64) {
        __syncthreads();
        gload16(ga, la0);
        gload16(ga + gstep, la0 + 2048);
        gload16(gb, lb0);
        gload16(gb + gstep, lb0 + 2048);
        gload16(ga + 32, la1);
        gload16(ga + 32 + gstep, la1 + 2048);
        gload16(gb + 32, lb1);
        gload16(gb + 32 + gstep, lb1 + 2048);
        ga += 64; gb += 64;
        __syncthreads();
#pragma unroll
        for (int h = 0; h < 2; h++) {
            const u16* Ah = h ? As1 : As0;
            const u16* Bh = h ? Bs1 : Bs0;
            bf16x8 af[4], bfr[4];
#pragma unroll
            for (int i = 0; i < 4; i++) {
                af[i]  = *(const bf16x8*)(Ah + (wm + i * 16 + fr) * 32 + quad * 8);
                bfr[i] = *(const bf16x8*)(Bh + (wn + i * 16 + fr) * 32 + quad * 8);
            }
#pragma unroll
            for (int i = 0; i < 4; i++)
#pragma unroll
                for (int j = 0; j < 4; j++)
                    acc[i][j] = __builtin_amdgcn_mfma_f32_16x16x32_bf16(
                        af[i], bfr[j], acc[i][j], 0, 0, 0);
        }
    }

    // C/D layout: row = quad*4 + reg, col = lane&15  [m89-verified]
    const int gr0 = bm * 128 + wm + quad * 4;
    const int gc0 = bn * 128 + wn + fr;
#pragma unroll
    for (int i = 0; i < 4; i++)
#pragma unroll
        for (int j = 0; j < 4; j++)
#pragma unroll
            for (int r = 0; r < 4; r++) {
                int gr = gr0 + i * 16 + r;
                int gc = gc0 + j * 16;
                float val = acc[i][j][r];
                if (BF16OUT)
                    ((u16*)Cout)[(size_t)gr * N + gc] = f2bf(val);
                else
                    ((float*)Cout)[(size_t)gr * N + gc] = val;
            }
}

// grouped GEMM for k/v/r (blockIdx.z selects operand set), bf16 out
// XCD swizzle: bm = x&63 -> XCD = x%8 = bm%8, so all 8 bn-blocks sharing an
// A row-block co-reside on one XCD (per-XCD L2 working set = 2MB A + 2MB W).
__global__ __launch_bounds__(256) void gemm3_kernel(
    const u16* __restrict__ xk, const u16* __restrict__ xv, const u16* __restrict__ xr,
    const u16* __restrict__ wk, const u16* __restrict__ wv, const u16* __restrict__ wr,
    u16* __restrict__ ck, u16* __restrict__ cv, u16* __restrict__ cr)
{
    __shared__ u16 As0[128 * 32], Bs0[128 * 32], As1[128 * 32], Bs1[128 * 32];
    const u16* A; const u16* Bw; u16* Cout;
    switch (blockIdx.z) {
        case 0:  A = xk; Bw = wk; Cout = ck; break;
        case 1:  A = xv; Bw = wv; Cout = cv; break;
        default: A = xr; Bw = wr; Cout = cr; break;
    }
    int bx = blockIdx.x;
    gemm_body<1>(A, Bw, (void*)Cout, As0, Bs0, As1, Bs1, bx & 63, bx >> 6);
}

// final GEMM, f32 out
__global__ __launch_bounds__(256) void gemmo_kernel(
    const u16* __restrict__ A, const u16* __restrict__ Bw, float* __restrict__ Cout)
{
    __shared__ u16 As0[128 * 32], Bs0[128 * 32], As1[128 * 32], Bs1[128 * 32];
    int bx = blockIdx.x;
    gemm_body<0>(A, Bw, (void*)Cout, As0, Bs0, As1, Bs1, bx & 63, bx >> 6);
}

// ---- WKV scan + sigmoid(r) gate; register double-buffered prefetch ------------
#define WTC 16

#define LOADCHUNK(KA, VA, RA, T0)                                        \
    _Pragma("unroll")                                                    \
    for (int s = 0; s < WTC; s++) {                                      \
        size_t idx = base + (size_t)((T0) + s) * Cdim;                   \
        KA[s] = kb[idx]; VA[s] = vb[idx]; RA[s] = rb[idx];               \
    }

#define COMPCHUNK(KA, VA, RA, T0)                                        \
    _Pragma("unroll")                                                    \
    for (int s = 0; s < WTC; s++) {                                      \
        float kt = bf2f(KA[s]);                                          \
        float vt = bf2f(VA[s]);                                          \
        float rt = bf2f(RA[s]);                                          \
        float uk = u + kt;                                               \
        float no = fmaxf(o, uk);                                         \
        float Ae = __expf(o - no);                                       \
        float Bc = __expf(uk - no);                                      \
        float num = Ae * p + Bc * vt;                                    \
        float den = Ae * q + Bc;                                         \
        float y = num * __builtin_amdgcn_rcpf(den);                      \
        float sr = __builtin_amdgcn_rcpf(1.f + __expf(-rt));             \
        rwkv[base + (size_t)((T0) + s) * Cdim] = f2bf(y * sr);           \
        float wo = w + o;                                                \
        float no2 = fmaxf(wo, kt);                                       \
        float A2 = __expf(wo - no2);                                     \
        float B2 = __expf(kt - no2);                                     \
        p = A2 * p + B2 * vt;                                            \
        q = A2 * q + B2;                                                 \
        o = no2;                                                         \
    }

__global__ __launch_bounds__(64) void wkv_kernel(
    const u16* __restrict__ kb, const u16* __restrict__ vb,
    const u16* __restrict__ rb, const float* __restrict__ td,
    const float* __restrict__ tfirst, u16* __restrict__ rwkv)
{
    int lane = threadIdx.x;
    int blk = blockIdx.x;            // 512 blocks
    int b = blk >> 4;
    int c = ((blk & 15) << 6) + lane;
    float w = -__expf(td[c]);
    float u = tfirst[c];
    const size_t base = (size_t)b * Tdim * Cdim + c;

    u32 kA[WTC], vA[WTC], rA[WTC];
    u32 kB[WTC], vB[WTC], rB[WTC];
    float p = 0.f, q = 0.f, o = -1e38f;

    LOADCHUNK(kA, vA, rA, 0)
    for (int t0 = 0; t0 < Tdim; t0 += 2 * WTC) {
        LOADCHUNK(kB, vB, rB, t0 + WTC)
        COMPCHUNK(kA, vA, rA, t0)
        if (t0 + 2 * WTC < Tdim) {
            LOADCHUNK(kA, vA, rA, t0 + 2 * WTC)
        }
        COMPCHUNK(kB, vB, rB, t0 + WTC)
    }
}

extern "C" void kernel_launch(void* const* d_in, const int* in_sizes, int n_in,
                              void* d_out, int out_size, void* d_ws, size_t ws_size,
                              hipStream_t stream) {
    (void)in_sizes; (void)n_in; (void)out_size; (void)ws_size;
    const float* x   = (const float*)d_in[0];
    const float* td  = (const float*)d_in[1];
    const float* tfi = (const float*)d_in[2];
    const float* tmk = (const float*)d_in[3];
    const float* tmv = (const float*)d_in[4];
    const float* tmr = (const float*)d_in[5];
    const float* Wk  = (const float*)d_in[6];
    const float* Wv  = (const float*)d_in[7];
    const float* Wr  = (const float*)d_in[8];
    const float* Wo  = (const float*)d_in[9];

    char* ws = (char*)d_ws;
    const size_t MiB = (size_t)1 << 20;
    u16* xk    = (u16*)(ws);             // [0,16)
    u16* xv    = (u16*)(ws + 16 * MiB);  // [16,32)
    u16* xr    = (u16*)(ws + 32 * MiB);  // [32,48)
    u16* wkb   = (u16*)(ws + 48 * MiB);  // [48,50)
    u16* wvb   = (u16*)(ws + 50 * MiB);  // [50,52)
    u16* wrb   = (u16*)(ws + 52 * MiB);  // [52,54)
    u16* wob   = (u16*)(ws + 54 * MiB);  // [54,56)
    u16* kb    = (u16*)(ws + 56 * MiB);  // [56,72)
    u16* vb    = (u16*)(ws + 72 * MiB);  // [72,88)
    u16* rb    = (u16*)(ws + 88 * MiB);  // [88,104) — no alias: gemm3 z's run concurrently
    u16* rwkvb = (u16*)(ws);             // [0,16) — overlaps xk (dead after gemm3)

    prep_fused<<<6144, 256, 0, stream>>>(x, tmk, tmv, tmr, xk, xv, xr,
                                         Wk, Wv, Wr, Wo, wkb, wvb, wrb, wob);

    gemm3_kernel<<<dim3(512, 1, 3), 256, 0, stream>>>(xk, xv, xr, wkb, wvb, wrb,
                                                      kb, vb, rb);

    wkv_kernel<<<512, 64, 0, stream>>>(kb, vb, rb, td, tfi, rwkvb);

    gemmo_kernel<<<512, 256, 0, stream>>>(rwkvb, wob, (float*)d_out);
}